// Round 6
// baseline (1587.348 us; speedup 1.0000x reference)
//
#include <hip/hip_runtime.h>

#define ALPHA 0.2f
__device__ __forceinline__ float lrelu_f(float x){ return x>0.f ? x : ALPHA*x; }
__device__ __forceinline__ float4 zero4(){ float4 z; z.x=z.y=z.z=z.w=0.f; return z; }

// XCD-chunk swizzle: bijective iff grid%8==0; identity fallback otherwise.
__device__ __forceinline__ int swz_bid(){
  int nb = gridDim.x, b = blockIdx.x;
  return ((nb & 7)==0) ? ((b & 7)*(nb>>3) + (b>>3)) : b;
}

// ============ enc1: 3x3 s2 SAME, NHWC(3ch) -> BLOCKED [N,8,128,128,4] ============
// Pixel-per-thread, all 32 couts; weights (864 floats) in LDS; stores coalesced per plane.
template<int H,int W,bool LRELU>   // H=W=256 input
__global__ __launch_bounds__(256) void enc1_blk_k(const float* __restrict__ in,
    const float* __restrict__ w, const float* __restrict__ bias, float* __restrict__ out){
  constexpr int Ho=H/2, Wo=W/2, COUT=32, PO=COUT/4;   // Wo=128
  __shared__ float wlds[9*3*COUT];                     // 864 floats
  if (threadIdx.x < (9*3*COUT)/4)
    ((float4*)wlds)[threadIdx.x] = ((const float4*)w)[threadIdx.x];
  __syncthreads();

  int lb = swz_bid();
  int yg = lb % (Ho/2); int n = lb / (Ho/2);
  int x  = threadIdx.x & (Wo-1) & 127;                 // Wo=128
  int yr = threadIdx.x >> 7;
  int y  = yg*2 + yr;

  float acc[COUT];
  #pragma unroll
  for (int j4=0;j4<PO;j4++){
    float4 bv = *(const float4*)(bias + j4*4);
    acc[j4*4+0]=bv.x; acc[j4*4+1]=bv.y; acc[j4*4+2]=bv.z; acc[j4*4+3]=bv.w;
  }

  #pragma unroll
  for (int ky=0;ky<3;ky++){
    int iy = 2*y + ky;
    bool oky = iy < H;
    const float* rp = in + ((size_t)n*H + (oky?iy:0))*(size_t)(W*3);
    #pragma unroll
    for (int kx=0;kx<3;kx++){
      int ix = 2*x + kx;
      bool ok = oky && (ix < W);
      const float* pp = rp + (size_t)(ok?ix:0)*3;
      float v0 = ok ? pp[0] : 0.f, v1 = ok ? pp[1] : 0.f, v2 = ok ? pp[2] : 0.f;
      const float* wp = wlds + ((ky*3+kx)*3)*COUT;
      #pragma unroll
      for (int j4=0;j4<PO;j4++){
        float4 w0 = *(const float4*)(wp + 0*COUT + j4*4);
        float4 w1 = *(const float4*)(wp + 1*COUT + j4*4);
        float4 w2 = *(const float4*)(wp + 2*COUT + j4*4);
        acc[j4*4+0] += v0*w0.x + v1*w1.x + v2*w2.x;
        acc[j4*4+1] += v0*w0.y + v1*w1.y + v2*w2.y;
        acc[j4*4+2] += v0*w0.z + v1*w1.z + v2*w2.z;
        acc[j4*4+3] += v0*w0.w + v1*w1.w + v2*w2.w;
      }
    }
  }
  #pragma unroll
  for (int p=0;p<PO;p++){
    float4 r;
    r.x = LRELU?lrelu_f(acc[p*4+0]):acc[p*4+0];
    r.y = LRELU?lrelu_f(acc[p*4+1]):acc[p*4+1];
    r.z = LRELU?lrelu_f(acc[p*4+2]):acc[p*4+2];
    r.w = LRELU?lrelu_f(acc[p*4+3]):acc[p*4+3];
    *(float4*)(out + (((size_t)(n*PO+p)*Ho + y)*Wo + x)*4) = r;
  }
}

// ============ Encoder 3x3 s2 SAME, BLOCKED in/out; ob block-level, weights in LDS ======
template<int H,int W,int CIN,int COUT,int TO,int TX,bool LRELU>
__global__ __launch_bounds__(256) void conv3x3_s2_blk_k(const float* __restrict__ in,
    const float* __restrict__ w, const float* __restrict__ bias, float* __restrict__ out){
  constexpr int Ho=H/2, Wo=W/2, OB=COUT/TO, XB=Wo/TX, TYR=256/XB, YG=Ho/TYR;
  constexpr int PI=CIN/4, PO=COUT/4, WN=9*CIN*TO;
  static_assert(256 % XB == 0 && Ho % TYR == 0, "geometry");
  __shared__ float wlds[WN];

  int lb = swz_bid();
  int ob = lb % OB; int g = lb / OB;
  int yg = g % YG;  int n  = g / YG;
  int xb = threadIdx.x % XB, yr = threadIdx.x / XB;
  int y = yg*TYR + yr, x0 = xb*TX;

  {
    const int base = ob*TO;
    for (int i = threadIdx.x; i < WN/4; i += 256){
      int j4 = i % (TO/4); int rest = i / (TO/4);
      ((float4*)wlds)[i] = *(const float4*)(w + (size_t)rest*COUT + base + j4*4);
    }
  }
  __syncthreads();

  float acc[TX][TO];
  #pragma unroll
  for (int j4=0;j4<TO/4;j4++){
    float4 bv = *(const float4*)(bias + ob*TO + j4*4);
    #pragma unroll
    for (int px=0;px<TX;px++){
      acc[px][j4*4+0]=bv.x; acc[px][j4*4+1]=bv.y;
      acc[px][j4*4+2]=bv.z; acc[px][j4*4+3]=bv.w;
    }
  }

  const float* nin = in + (size_t)n*PI*H*(size_t)(W*4);
  for (int pc=0; pc<PI; ++pc){
    const float* pbase = nin + (size_t)pc*H*(size_t)(W*4);
    float4 v[3][2*TX+1];
    #pragma unroll
    for (int ky=0;ky<3;ky++){
      int iy = 2*y + ky;
      bool oky = iy < H;
      const float* rp = pbase + (size_t)(oky?iy:0)*(W*4);
      #pragma unroll
      for (int j=0;j<2*TX+1;j++){
        int ix = 2*x0 + j;
        bool ok = oky && (ix < W);
        float4 a = *(const float4*)(rp + (ok?ix:0)*4);
        if (!ok) a = zero4();
        v[ky][j] = a;
      }
    }
    const int c = pc*4;
    #pragma unroll
    for (int ky=0;ky<3;ky++){
      #pragma unroll
      for (int kx=0;kx<3;kx++){
        const float* wp = wlds + ((ky*3+kx)*CIN + c)*TO;
        float4 wv[4][TO/4];
        #pragma unroll
        for (int ci=0;ci<4;ci++)
          #pragma unroll
          for (int j4=0;j4<TO/4;j4++)
            wv[ci][j4] = *(const float4*)(wp + ci*TO + j4*4);
        #pragma unroll
        for (int px=0;px<TX;px++){
          float4 vv = v[ky][2*px+kx];
          float vc[4] = {vv.x, vv.y, vv.z, vv.w};
          #pragma unroll
          for (int ci=0;ci<4;ci++)
            #pragma unroll
            for (int j4=0;j4<TO/4;j4++){
              acc[px][j4*4+0] += vc[ci]*wv[ci][j4].x;
              acc[px][j4*4+1] += vc[ci]*wv[ci][j4].y;
              acc[px][j4*4+2] += vc[ci]*wv[ci][j4].z;
              acc[px][j4*4+3] += vc[ci]*wv[ci][j4].w;
            }
        }
      }
    }
  }

  float* nout = out + (size_t)n*PO*Ho*(size_t)(Wo*4);
  #pragma unroll
  for (int h2=0; h2<TO/4; ++h2){
    int pp = ob*(TO/4) + h2;
    float* op = nout + ((size_t)pp*Ho + y)*(size_t)(Wo*4) + (size_t)x0*4;
    #pragma unroll
    for (int px=0;px<TX;px++){
      float4 r;
      r.x = LRELU?lrelu_f(acc[px][h2*4+0]):acc[px][h2*4+0];
      r.y = LRELU?lrelu_f(acc[px][h2*4+1]):acc[px][h2*4+1];
      r.z = LRELU?lrelu_f(acc[px][h2*4+2]):acc[px][h2*4+2];
      r.w = LRELU?lrelu_f(acc[px][h2*4+3]):acc[px][h2*4+3];
      *(float4*)(op + px*4) = r;
    }
  }
}

// ============ Fused enc4 (1x1 conv 64->32) + VQ; BLOCKED in [N,16,PIXI,4] and out ============
template<int CIN,int D,int K,int PIXI>
__global__ __launch_bounds__(256) void enc4_vq_k(const float* __restrict__ in,
    const float* __restrict__ w, const float* __restrict__ bias,
    const float* __restrict__ cb, float* __restrict__ q, int npix){
  constexpr int PIN = CIN/4;
  int i = blockIdx.x*256 + threadIdx.x;
  if (i >= npix) return;
  int n = i / PIXI, pix = i % PIXI;
  float z[D];
  #pragma unroll
  for (int d=0; d<D; d++) z[d] = bias[d];
  #pragma unroll
  for (int pc=0; pc<PIN; ++pc){
    float4 v = *(const float4*)(in + ((size_t)(n*PIN+pc)*PIXI + pix)*4);
    const int c = pc*4;
    #pragma unroll
    for (int d=0; d<D; d++){
      z[d] += v.x * w[(c+0)*D + d];
      z[d] += v.y * w[(c+1)*D + d];
      z[d] += v.z * w[(c+2)*D + d];
      z[d] += v.w * w[(c+3)*D + d];
    }
  }
  float z2 = 0.f;
  #pragma unroll
  for (int d=0; d<D; d++) z2 += z[d]*z[d];
  float best = 3.4e38f; int bi = 0;
  for (int k=0; k<K; k++){
    float e2 = 0.f, dot = 0.f;
    #pragma unroll
    for (int d=0; d<D; d++){
      float cv = cb[d*K + k];
      e2  += cv*cv;
      dot += z[d]*cv;
    }
    float dist = z2 + e2 - 2.f*dot;
    if (dist < best){ best = dist; bi = k; }   // strict < == first-min (jnp.argmin)
  }
  #pragma unroll
  for (int p=0; p<D/4; p++){
    float4 f;
    f.x = cb[(4*p+0)*K + bi]; f.y = cb[(4*p+1)*K + bi];
    f.z = cb[(4*p+2)*K + bi]; f.w = cb[(4*p+3)*K + bi];
    *(float4*)(q + ((size_t)(n*(D/4)+p)*PIXI + pix)*4) = f;
  }
}

// ======== Parity-fused deconv 3x3 s2 SAME, BLOCKED in/out, 2-deep register prefetch ========
template<int H,int W,int CIN,int COUT,int TO,int TX,bool LRELU>
__global__ __launch_bounds__(256) void deconv3x3_s2_blk_k(const float* __restrict__ in,
    const float* __restrict__ w, const float* __restrict__ bias, float* __restrict__ out){
  constexpr int Ho=2*H, Wo=2*W, OB=COUT/TO, XB2=W/TX, TYR=256/XB2, YG=H/TYR;
  constexpr int PI=CIN/4, PO=COUT/4;
  constexpr int WN = 9*CIN*TO;
  static_assert(256 % XB2 == 0 && H % TYR == 0 && (PI%2)==0, "geometry");
  __shared__ float wlds[WN];

  int lb = swz_bid();
  int ob = lb % OB; int g = lb / OB;
  int yg = g % YG;  int n  = g / YG;
  int xb = threadIdx.x % XB2, yr = threadIdx.x / XB2;
  int yy = yg*TYR + yr, x0 = xb*TX;

  {
    const int base = ob*TO;
    for (int i = threadIdx.x; i < WN/4; i += 256){
      int j4 = i % (TO/4); int rest = i / (TO/4);
      ((float4*)wlds)[i] = *(const float4*)(w + (size_t)rest*COUT + base + j4*4);
    }
  }
  __syncthreads();

  float acc[2][2*TX][TO];
  #pragma unroll
  for (int j4=0;j4<TO/4;j4++){
    float4 bv = *(const float4*)(bias + ob*TO + j4*4);
    #pragma unroll
    for (int py=0;py<2;py++)
      #pragma unroll
      for (int q=0;q<2*TX;q++){
        acc[py][q][j4*4+0]=bv.x; acc[py][q][j4*4+1]=bv.y;
        acc[py][q][j4*4+2]=bv.z; acc[py][q][j4*4+3]=bv.w;
      }
  }

  const bool has0 = (yy > 0);
  const float* nin = in + (size_t)n*PI*H*(size_t)(W*4);

  auto ldchunk = [&](int pc, float4 (&v0)[TX+1], float4 (&v1)[TX+1]){
    const float* pbase = nin + (size_t)pc*H*(size_t)(W*4);
    const float* r1p = pbase + (size_t)yy*(W*4);
    const float* r0p = pbase + (size_t)(has0 ? yy-1 : 0)*(W*4);
    #pragma unroll
    for (int j=0;j<=TX;j++){
      int xi = x0 - 1 + j;
      bool ok = (xi >= 0);
      int off = (ok ? xi : 0)*4;
      float4 a1 = *(const float4*)(r1p + off);
      float4 a0 = has0 ? *(const float4*)(r0p + off) : zero4();
      if (!ok){ a1 = zero4(); a0 = zero4(); }
      v1[j] = a1; v0[j] = a0;
    }
  };
  auto compute = [&](int pc, float4 (&v0)[TX+1], float4 (&v1)[TX+1]){
    const int c = pc*4;
    #pragma unroll
    for (int ky=0;ky<3;ky++){
      const int py = (ky==1) ? 1 : 0;
      #pragma unroll
      for (int kx=0;kx<3;kx++){
        const int pxp = (kx==1) ? 1 : 0;
        const float* wp = wlds + ((ky*3+kx)*CIN + c)*TO;
        float4 wv[4][TO/4];
        #pragma unroll
        for (int ci=0;ci<4;ci++)
          #pragma unroll
          for (int j4=0;j4<TO/4;j4++)
            wv[ci][j4] = *(const float4*)(wp + ci*TO + j4*4);
        #pragma unroll
        for (int px=0;px<TX;px++){
          const int jj = (kx==0) ? px : (px+1);
          float4 vv = (ky==0) ? v0[jj] : v1[jj];
          float vc[4] = {vv.x, vv.y, vv.z, vv.w};
          #pragma unroll
          for (int ci=0;ci<4;ci++)
            #pragma unroll
            for (int j4=0;j4<TO/4;j4++){
              acc[py][2*px+pxp][j4*4+0] += vc[ci]*wv[ci][j4].x;
              acc[py][2*px+pxp][j4*4+1] += vc[ci]*wv[ci][j4].y;
              acc[py][2*px+pxp][j4*4+2] += vc[ci]*wv[ci][j4].z;
              acc[py][2*px+pxp][j4*4+3] += vc[ci]*wv[ci][j4].w;
            }
        }
      }
    }
  };

  // static 2-deep pipeline (named buffers, compile-time indices)
  float4 vA0[TX+1], vA1[TX+1], vB0[TX+1], vB1[TX+1];
  ldchunk(0, vA0, vA1);
  for (int pc=0; pc<PI; pc+=2){
    ldchunk(pc+1, vB0, vB1);
    compute(pc, vA0, vA1);
    if (pc+2 < PI) ldchunk(pc+2, vA0, vA1);
    compute(pc+1, vB0, vB1);
  }

  float* nout = out + (size_t)n*PO*Ho*(size_t)(Wo*4);
  #pragma unroll
  for (int py=0;py<2;py++){
    int yo = 2*yy + py;
    #pragma unroll
    for (int h2=0; h2<TO/4; ++h2){
      int pp = ob*(TO/4) + h2;
      float* op = nout + ((size_t)pp*Ho + yo)*(size_t)(Wo*4) + (size_t)(2*x0)*4;
      #pragma unroll
      for (int q=0;q<2*TX;q++){
        float4 r;
        r.x = LRELU?lrelu_f(acc[py][q][h2*4+0]):acc[py][q][h2*4+0];
        r.y = LRELU?lrelu_f(acc[py][q][h2*4+1]):acc[py][q][h2*4+1];
        r.z = LRELU?lrelu_f(acc[py][q][h2*4+2]):acc[py][q][h2*4+2];
        r.w = LRELU?lrelu_f(acc[py][q][h2*4+3]):acc[py][q][h2*4+3];
        *(float4*)(op + q*4) = r;
      }
    }
  }
}

// ============ dec4: 3x3 pad-1 conv, Cout=1 — LDS-tiled, BLOCKED input ============
template<int H,int W,int CIN>
__global__ __launch_bounds__(256) void dec4_tiled_k(const float* __restrict__ in,
    const float* __restrict__ w, const float* __restrict__ bias, float* __restrict__ out){
  constexpr int TX=4, WB=128, TYB=8, GX=W/WB, GY=H/TYB, COLS=WB+2, ROWS=TYB+2;
  constexpr int NPIX = ROWS*COLS;
  constexpr int PI = CIN/4;
  __shared__ float4 tile[2*NPIX];
  __shared__ float4 wsh[(9*CIN)/4];

  int lb = swz_bid();
  int gx = lb % GX; int rest = lb / GX;
  int yg = rest % GY; int n = rest / GY;
  int xb = threadIdx.x & 31, yr = threadIdx.x >> 5;
  int y0 = yg*TYB, xbase = gx*WB;

  if (threadIdx.x < (9*CIN)/4) wsh[threadIdx.x] = ((const float4*)w)[threadIdx.x];

  const float* nin = in + (size_t)n*PI*H*(size_t)(W*4);

  float b0 = bias[0];
  float acc[TX];
  #pragma unroll
  for (int px=0;px<TX;px++) acc[px] = b0;

  for (int cc=0; cc<CIN/8; ++cc){
    __syncthreads();
    const float* p0 = nin + (size_t)(2*cc  )*H*(size_t)(W*4);
    const float* p1 = nin + (size_t)(2*cc+1)*H*(size_t)(W*4);
    for (int i = threadIdx.x; i < NPIX; i += 256){
      int row = i / COLS, col = i % COLS;
      int grow = y0 - 1 + row, gcol = xbase - 1 + col;
      float4 a0 = zero4(), a1 = zero4();
      if ((unsigned)grow < (unsigned)H && (unsigned)gcol < (unsigned)W){
        size_t off = (size_t)grow*(W*4) + (size_t)gcol*4;
        a0 = *(const float4*)(p0 + off); a1 = *(const float4*)(p1 + off);
      }
      int p = row*COLS + (col ^ ((col>>2)&7));
      tile[p] = a0; tile[NPIX + p] = a1;
    }
    __syncthreads();

    #pragma unroll
    for (int ky=0;ky<3;ky++){
      int rowb = (yr + ky)*COLS;
      float4 w0[3], w1[3];
      #pragma unroll
      for (int kx=0;kx<3;kx++){
        int tf = (ky*3+kx)*(CIN/4) + cc*2;
        w0[kx] = wsh[tf]; w1[kx] = wsh[tf+1];
      }
      #pragma unroll
      for (int j=0;j<TX+2;j++){
        int col = 4*xb + j;
        int p = rowb + (col ^ ((col>>2)&7));
        float4 a0 = tile[p], a1 = tile[NPIX + p];
        #pragma unroll
        for (int kx=0;kx<3;kx++){
          int px = j - kx;
          if (px >= 0 && px < TX){
            acc[px] += a0.x*w0[kx].x + a0.y*w0[kx].y + a0.z*w0[kx].z + a0.w*w0[kx].w
                     + a1.x*w1[kx].x + a1.y*w1[kx].y + a1.z*w1[kx].z + a1.w*w1[kx].w;
          }
        }
      }
    }
  }

  int y = y0 + yr;
  float* op = out + ((size_t)n*H + y)*(size_t)W + xbase + 4*xb;
  float4 r; r.x=acc[0]; r.y=acc[1]; r.z=acc[2]; r.w=acc[3];
  *(float4*)op = r;
}

extern "C" void kernel_launch(void* const* d_in, const int* in_sizes, int n_in,
                              void* d_out, int out_size, void* d_ws, size_t ws_size,
                              hipStream_t stream) {
  const float* x   = (const float*)d_in[0];
  const float* e1w = (const float*)d_in[1];  const float* e1b = (const float*)d_in[2];
  const float* e2w = (const float*)d_in[3];  const float* e2b = (const float*)d_in[4];
  const float* e3w = (const float*)d_in[5];  const float* e3b = (const float*)d_in[6];
  const float* e4w = (const float*)d_in[7];  const float* e4b = (const float*)d_in[8];
  const float* cb  = (const float*)d_in[9];
  const float* d1w = (const float*)d_in[10]; const float* d1b = (const float*)d_in[11];
  const float* d2w = (const float*)d_in[12]; const float* d2b = (const float*)d_in[13];
  const float* d3w = (const float*)d_in[14]; const float* d3b = (const float*)d_in[15];
  const float* d4w = (const float*)d_in[16]; const float* d4b = (const float*)d_in[17];
  float* out = (float*)d_out;

  const size_t MiB = 1ull << 20;
  int Bc = 32;
  while (Bc > 1 && (size_t)Bc * 12 * MiB > ws_size) Bc >>= 1;

  char* wsb = (char*)d_ws;
  float* A  = (float*)wsb;                              // Bc * 8 MiB
  float* Bf = (float*)(wsb + (size_t)Bc * 8 * MiB);     // Bc * 4 MiB

  for (int n0 = 0; n0 < 32; n0 += Bc) {
    const float* xc = x   + (size_t)n0 * 256*256*3;
    float*      oc  = out + (size_t)n0 * 256*256;

    // enc1: NHWC x -> h1 [Bc,8,128,128,4]; pixel/thread, grid = Bc*64
    enc1_blk_k<256,256,true><<<Bc*64,256,0,stream>>>(xc, e1w, e1b, A);
    // enc2: -> h2 [Bc,16,64,64,4]; OB=8,XB=32,TYR=8,YG=8 -> Bc*64
    conv3x3_s2_blk_k<128,128,32,64,8,2,true><<<Bc*64,256,0,stream>>>(A, e2w, e2b, Bf);
    // enc3: -> h3 [Bc,16,32,32,4]; OB=8,XB=16,TYR=16,YG=2 -> Bc*16
    conv3x3_s2_blk_k<64,64,64,64,8,2,true><<<Bc*16,256,0,stream>>>(Bf, e3w, e3b, A);
    // enc4 (1x1, 64->32) + VQ: -> q [Bc,8,32,32,4]
    int npix = Bc*32*32;
    enc4_vq_k<64,32,64,1024><<<npix/256,256,0,stream>>>(A, e4w, e4b, cb, Bf, npix);
    // dec1: q -> d1 [Bc,16,64,64,4]; XB2=16,TYR=16,YG=2,OB=8 -> Bc*16
    deconv3x3_s2_blk_k<32,32,32,64,8,2,true><<<Bc*16,256,0,stream>>>(Bf, d1w, d1b, A);
    // dec2: -> d2 [Bc,16,128,128,4]; XB2=32,TYR=8,YG=8,OB=8 -> Bc*64
    deconv3x3_s2_blk_k<64,64,64,64,8,2,true><<<Bc*64,256,0,stream>>>(A, d2w, d2b, Bf);
    // dec3: -> d3 [Bc,8,256,256,4]; XB2=64,TYR=4,YG=32,OB=4 -> Bc*128
    deconv3x3_s2_blk_k<128,128,64,32,8,2,true><<<Bc*128,256,0,stream>>>(Bf, d3w, d3b, A);
    // dec4: d3 BLOCKED -> [Bc,256,256,1]; LDS-tiled, grid = Bc*64
    dec4_tiled_k<256,256,32><<<Bc*64,256,0,stream>>>(A, d4w, d4b, oc);
  }
}

// Round 8
// 1217.170 us; speedup vs baseline: 1.3041x; 1.3041x over previous
//
#include <hip/hip_runtime.h>

#define ALPHA 0.2f
__device__ __forceinline__ float lrelu_f(float x){ return x>0.f ? x : ALPHA*x; }
__device__ __forceinline__ float4 zero4(){ float4 z; z.x=z.y=z.z=z.w=0.f; return z; }

// XCD-chunk swizzle: bijective iff grid%8==0; identity fallback otherwise.
__device__ __forceinline__ int swz_bid(){
  int nb = gridDim.x, b = blockIdx.x;
  return ((nb & 7)==0) ? ((b & 7)*(nb>>3) + (b>>3)) : b;
}

// ============ enc1: 3x3 s2 SAME, NHWC(3ch) -> BLOCKED [N,8,128,128,4] ============
template<int H,int W,bool LRELU>   // H=W=256 input
__global__ __launch_bounds__(256) void enc1_blk_k(const float* __restrict__ in,
    const float* __restrict__ w, const float* __restrict__ bias, float* __restrict__ out){
  constexpr int Ho=H/2, Wo=W/2, COUT=32, PO=COUT/4;   // Wo=128
  __shared__ float wlds[9*3*COUT];                     // 864 floats
  if (threadIdx.x < (9*3*COUT)/4)
    ((float4*)wlds)[threadIdx.x] = ((const float4*)w)[threadIdx.x];
  __syncthreads();

  int lb = swz_bid();
  int yg = lb % (Ho/2); int n = lb / (Ho/2);
  int x  = threadIdx.x & 127;                          // Wo=128
  int yr = threadIdx.x >> 7;
  int y  = yg*2 + yr;

  float acc[COUT];
  #pragma unroll
  for (int j4=0;j4<PO;j4++){
    float4 bv = *(const float4*)(bias + j4*4);
    acc[j4*4+0]=bv.x; acc[j4*4+1]=bv.y; acc[j4*4+2]=bv.z; acc[j4*4+3]=bv.w;
  }

  #pragma unroll
  for (int ky=0;ky<3;ky++){
    int iy = 2*y + ky;
    bool oky = iy < H;
    const float* rp = in + ((size_t)n*H + (oky?iy:0))*(size_t)(W*3);
    #pragma unroll
    for (int kx=0;kx<3;kx++){
      int ix = 2*x + kx;
      bool ok = oky && (ix < W);
      const float* pp = rp + (size_t)(ok?ix:0)*3;
      float v0 = ok ? pp[0] : 0.f, v1 = ok ? pp[1] : 0.f, v2 = ok ? pp[2] : 0.f;
      const float* wp = wlds + ((ky*3+kx)*3)*COUT;
      #pragma unroll
      for (int j4=0;j4<PO;j4++){
        float4 w0 = *(const float4*)(wp + 0*COUT + j4*4);
        float4 w1 = *(const float4*)(wp + 1*COUT + j4*4);
        float4 w2 = *(const float4*)(wp + 2*COUT + j4*4);
        acc[j4*4+0] += v0*w0.x + v1*w1.x + v2*w2.x;
        acc[j4*4+1] += v0*w0.y + v1*w1.y + v2*w2.y;
        acc[j4*4+2] += v0*w0.z + v1*w1.z + v2*w2.z;
        acc[j4*4+3] += v0*w0.w + v1*w1.w + v2*w2.w;
      }
    }
  }
  #pragma unroll
  for (int p=0;p<PO;p++){
    float4 r;
    r.x = LRELU?lrelu_f(acc[p*4+0]):acc[p*4+0];
    r.y = LRELU?lrelu_f(acc[p*4+1]):acc[p*4+1];
    r.z = LRELU?lrelu_f(acc[p*4+2]):acc[p*4+2];
    r.w = LRELU?lrelu_f(acc[p*4+3]):acc[p*4+3];
    *(float4*)(out + (((size_t)(n*PO+p)*Ho + y)*Wo + x)*4) = r;
  }
}

// ============ Encoder 3x3 s2 SAME, BLOCKED in/out; ob block-level, weights in LDS ======
template<int H,int W,int CIN,int COUT,int TO,int TX,bool LRELU>
__global__ __launch_bounds__(256) void conv3x3_s2_blk_k(const float* __restrict__ in,
    const float* __restrict__ w, const float* __restrict__ bias, float* __restrict__ out){
  constexpr int Ho=H/2, Wo=W/2, OB=COUT/TO, XB=Wo/TX, TYR=256/XB, YG=Ho/TYR;
  constexpr int PI=CIN/4, PO=COUT/4, WN=9*CIN*TO;
  static_assert(256 % XB == 0 && Ho % TYR == 0, "geometry");
  __shared__ float wlds[WN];

  int lb = swz_bid();
  int ob = lb % OB; int g = lb / OB;
  int yg = g % YG;  int n  = g / YG;
  int xb = threadIdx.x % XB, yr = threadIdx.x / XB;
  int y = yg*TYR + yr, x0 = xb*TX;

  {
    const int base = ob*TO;
    for (int i = threadIdx.x; i < WN/4; i += 256){
      int j4 = i % (TO/4); int rest = i / (TO/4);
      ((float4*)wlds)[i] = *(const float4*)(w + (size_t)rest*COUT + base + j4*4);
    }
  }
  __syncthreads();

  float acc[TX][TO];
  #pragma unroll
  for (int j4=0;j4<TO/4;j4++){
    float4 bv = *(const float4*)(bias + ob*TO + j4*4);
    #pragma unroll
    for (int px=0;px<TX;px++){
      acc[px][j4*4+0]=bv.x; acc[px][j4*4+1]=bv.y;
      acc[px][j4*4+2]=bv.z; acc[px][j4*4+3]=bv.w;
    }
  }

  const float* nin = in + (size_t)n*PI*H*(size_t)(W*4);
  for (int pc=0; pc<PI; ++pc){
    const float* pbase = nin + (size_t)pc*H*(size_t)(W*4);
    float4 v[3][2*TX+1];
    #pragma unroll
    for (int ky=0;ky<3;ky++){
      int iy = 2*y + ky;
      bool oky = iy < H;
      const float* rp = pbase + (size_t)(oky?iy:0)*(W*4);
      #pragma unroll
      for (int j=0;j<2*TX+1;j++){
        int ix = 2*x0 + j;
        bool ok = oky && (ix < W);
        float4 a = *(const float4*)(rp + (ok?ix:0)*4);
        if (!ok) a = zero4();
        v[ky][j] = a;
      }
    }
    const int c = pc*4;
    #pragma unroll
    for (int ky=0;ky<3;ky++){
      #pragma unroll
      for (int kx=0;kx<3;kx++){
        const float* wp = wlds + ((ky*3+kx)*CIN + c)*TO;
        float4 wv[4][TO/4];
        #pragma unroll
        for (int ci=0;ci<4;ci++)
          #pragma unroll
          for (int j4=0;j4<TO/4;j4++)
            wv[ci][j4] = *(const float4*)(wp + ci*TO + j4*4);
        #pragma unroll
        for (int px=0;px<TX;px++){
          float4 vv = v[ky][2*px+kx];
          float vc[4] = {vv.x, vv.y, vv.z, vv.w};
          #pragma unroll
          for (int ci=0;ci<4;ci++)
            #pragma unroll
            for (int j4=0;j4<TO/4;j4++){
              acc[px][j4*4+0] += vc[ci]*wv[ci][j4].x;
              acc[px][j4*4+1] += vc[ci]*wv[ci][j4].y;
              acc[px][j4*4+2] += vc[ci]*wv[ci][j4].z;
              acc[px][j4*4+3] += vc[ci]*wv[ci][j4].w;
            }
        }
      }
    }
  }

  float* nout = out + (size_t)n*PO*Ho*(size_t)(Wo*4);
  #pragma unroll
  for (int h2=0; h2<TO/4; ++h2){
    int pp = ob*(TO/4) + h2;
    float* op = nout + ((size_t)pp*Ho + y)*(size_t)(Wo*4) + (size_t)x0*4;
    #pragma unroll
    for (int px=0;px<TX;px++){
      float4 r;
      r.x = LRELU?lrelu_f(acc[px][h2*4+0]):acc[px][h2*4+0];
      r.y = LRELU?lrelu_f(acc[px][h2*4+1]):acc[px][h2*4+1];
      r.z = LRELU?lrelu_f(acc[px][h2*4+2]):acc[px][h2*4+2];
      r.w = LRELU?lrelu_f(acc[px][h2*4+3]):acc[px][h2*4+3];
      *(float4*)(op + px*4) = r;
    }
  }
}

// ============ Fused enc4 (1x1 conv 64->32) + VQ; BLOCKED in [N,16,PIXI,4] and out ============
template<int CIN,int D,int K,int PIXI>
__global__ __launch_bounds__(256) void enc4_vq_k(const float* __restrict__ in,
    const float* __restrict__ w, const float* __restrict__ bias,
    const float* __restrict__ cb, float* __restrict__ q, int npix){
  constexpr int PIN = CIN/4;
  int i = blockIdx.x*256 + threadIdx.x;
  if (i >= npix) return;
  int n = i / PIXI, pix = i % PIXI;
  float z[D];
  #pragma unroll
  for (int d=0; d<D; d++) z[d] = bias[d];
  #pragma unroll
  for (int pc=0; pc<PIN; ++pc){
    float4 v = *(const float4*)(in + ((size_t)(n*PIN+pc)*PIXI + pix)*4);
    const int c = pc*4;
    #pragma unroll
    for (int d=0; d<D; d++){
      z[d] += v.x * w[(c+0)*D + d];
      z[d] += v.y * w[(c+1)*D + d];
      z[d] += v.z * w[(c+2)*D + d];
      z[d] += v.w * w[(c+3)*D + d];
    }
  }
  float z2 = 0.f;
  #pragma unroll
  for (int d=0; d<D; d++) z2 += z[d]*z[d];
  float best = 3.4e38f; int bi = 0;
  for (int k=0; k<K; k++){
    float e2 = 0.f, dot = 0.f;
    #pragma unroll
    for (int d=0; d<D; d++){
      float cv = cb[d*K + k];
      e2  += cv*cv;
      dot += z[d]*cv;
    }
    float dist = z2 + e2 - 2.f*dot;
    if (dist < best){ best = dist; bi = k; }   // strict < == first-min (jnp.argmin)
  }
  #pragma unroll
  for (int p=0; p<D/4; p++){
    float4 f;
    f.x = cb[(4*p+0)*K + bi]; f.y = cb[(4*p+1)*K + bi];
    f.z = cb[(4*p+2)*K + bi]; f.w = cb[(4*p+3)*K + bi];
    *(float4*)(q + ((size_t)(n*(D/4)+p)*PIXI + pix)*4) = f;
  }
}

// ======== Parity-fused deconv 3x3 s2 SAME, BLOCKED in/out (round-5 verified body) ========
template<int H,int W,int CIN,int COUT,int TO,int TX,bool LRELU>
__global__ __launch_bounds__(256) void deconv3x3_s2_blk_k(const float* __restrict__ in,
    const float* __restrict__ w, const float* __restrict__ bias, float* __restrict__ out){
  constexpr int Ho=2*H, Wo=2*W, OB=COUT/TO, XB2=W/TX, TYR=256/XB2, YG=H/TYR;
  constexpr int PI=CIN/4, PO=COUT/4;
  constexpr int WN = 9*CIN*TO;
  static_assert(256 % XB2 == 0 && H % TYR == 0, "geometry");
  __shared__ float wlds[WN];

  int lb = swz_bid();
  int ob = lb % OB; int g = lb / OB;
  int yg = g % YG;  int n  = g / YG;
  int xb = threadIdx.x % XB2, yr = threadIdx.x / XB2;
  int yy = yg*TYR + yr, x0 = xb*TX;

  {
    const int base = ob*TO;
    for (int i = threadIdx.x; i < WN/4; i += 256){
      int j4 = i % (TO/4); int rest = i / (TO/4);
      ((float4*)wlds)[i] = *(const float4*)(w + (size_t)rest*COUT + base + j4*4);
    }
  }
  __syncthreads();

  float acc[2][2*TX][TO];
  #pragma unroll
  for (int j4=0;j4<TO/4;j4++){
    float4 bv = *(const float4*)(bias + ob*TO + j4*4);
    #pragma unroll
    for (int py=0;py<2;py++)
      #pragma unroll
      for (int q=0;q<2*TX;q++){
        acc[py][q][j4*4+0]=bv.x; acc[py][q][j4*4+1]=bv.y;
        acc[py][q][j4*4+2]=bv.z; acc[py][q][j4*4+3]=bv.w;
      }
  }

  const bool has0 = (yy > 0);
  const float* nin = in + (size_t)n*PI*H*(size_t)(W*4);

  for (int pc=0; pc<PI; ++pc){
    const float* pbase = nin + (size_t)pc*H*(size_t)(W*4);
    const float* r1p = pbase + (size_t)yy*(W*4);
    const float* r0p = pbase + (size_t)(has0 ? yy-1 : 0)*(W*4);
    float4 v0[TX+1], v1[TX+1];
    #pragma unroll
    for (int j=0;j<=TX;j++){
      int xi = x0 - 1 + j;
      bool ok = (xi >= 0);
      int off = (ok ? xi : 0)*4;
      float4 a1 = *(const float4*)(r1p + off);
      float4 a0 = has0 ? *(const float4*)(r0p + off) : zero4();
      if (!ok){ a1 = zero4(); a0 = zero4(); }
      v1[j] = a1; v0[j] = a0;
    }
    const int c = pc*4;
    #pragma unroll
    for (int ky=0;ky<3;ky++){
      const int py = (ky==1) ? 1 : 0;
      #pragma unroll
      for (int kx=0;kx<3;kx++){
        const int pxp = (kx==1) ? 1 : 0;
        const float* wp = wlds + ((ky*3+kx)*CIN + c)*TO;
        float4 wv[4][TO/4];
        #pragma unroll
        for (int ci=0;ci<4;ci++)
          #pragma unroll
          for (int j4=0;j4<TO/4;j4++)
            wv[ci][j4] = *(const float4*)(wp + ci*TO + j4*4);
        #pragma unroll
        for (int px=0;px<TX;px++){
          const int jj = (kx==0) ? px : (px+1);
          float4 vv = (ky==0) ? v0[jj] : v1[jj];
          float vc[4] = {vv.x, vv.y, vv.z, vv.w};
          #pragma unroll
          for (int ci=0;ci<4;ci++)
            #pragma unroll
            for (int j4=0;j4<TO/4;j4++){
              acc[py][2*px+pxp][j4*4+0] += vc[ci]*wv[ci][j4].x;
              acc[py][2*px+pxp][j4*4+1] += vc[ci]*wv[ci][j4].y;
              acc[py][2*px+pxp][j4*4+2] += vc[ci]*wv[ci][j4].z;
              acc[py][2*px+pxp][j4*4+3] += vc[ci]*wv[ci][j4].w;
            }
        }
      }
    }
  }

  float* nout = out + (size_t)n*PO*Ho*(size_t)(Wo*4);
  #pragma unroll
  for (int py=0;py<2;py++){
    int yo = 2*yy + py;
    #pragma unroll
    for (int h2=0; h2<TO/4; ++h2){
      int pp = ob*(TO/4) + h2;
      float* op = nout + ((size_t)pp*Ho + yo)*(size_t)(Wo*4) + (size_t)(2*x0)*4;
      #pragma unroll
      for (int q=0;q<2*TX;q++){
        float4 r;
        r.x = LRELU?lrelu_f(acc[py][q][h2*4+0]):acc[py][q][h2*4+0];
        r.y = LRELU?lrelu_f(acc[py][q][h2*4+1]):acc[py][q][h2*4+1];
        r.z = LRELU?lrelu_f(acc[py][q][h2*4+2]):acc[py][q][h2*4+2];
        r.w = LRELU?lrelu_f(acc[py][q][h2*4+3]):acc[py][q][h2*4+3];
        *(float4*)(op + q*4) = r;
      }
    }
  }
}

// ============ dec4: 3x3 pad-1 conv, Cout=1 — LDS-tiled, BLOCKED input ============
template<int H,int W,int CIN>
__global__ __launch_bounds__(256) void dec4_tiled_k(const float* __restrict__ in,
    const float* __restrict__ w, const float* __restrict__ bias, float* __restrict__ out){
  constexpr int TX=4, WB=128, TYB=8, GX=W/WB, GY=H/TYB, COLS=WB+2, ROWS=TYB+2;
  constexpr int NPIX = ROWS*COLS;
  constexpr int PI = CIN/4;
  __shared__ float4 tile[2*NPIX];
  __shared__ float4 wsh[(9*CIN)/4];

  int lb = swz_bid();
  int gx = lb % GX; int rest = lb / GX;
  int yg = rest % GY; int n = rest / GY;
  int xb = threadIdx.x & 31, yr = threadIdx.x >> 5;
  int y0 = yg*TYB, xbase = gx*WB;

  if (threadIdx.x < (9*CIN)/4) wsh[threadIdx.x] = ((const float4*)w)[threadIdx.x];

  const float* nin = in + (size_t)n*PI*H*(size_t)(W*4);

  float b0 = bias[0];
  float acc[TX];
  #pragma unroll
  for (int px=0;px<TX;px++) acc[px] = b0;

  for (int cc=0; cc<CIN/8; ++cc){
    __syncthreads();
    const float* p0 = nin + (size_t)(2*cc  )*H*(size_t)(W*4);
    const float* p1 = nin + (size_t)(2*cc+1)*H*(size_t)(W*4);
    for (int i = threadIdx.x; i < NPIX; i += 256){
      int row = i / COLS, col = i % COLS;
      int grow = y0 - 1 + row, gcol = xbase - 1 + col;
      float4 a0 = zero4(), a1 = zero4();
      if ((unsigned)grow < (unsigned)H && (unsigned)gcol < (unsigned)W){
        size_t off = (size_t)grow*(W*4) + (size_t)gcol*4;
        a0 = *(const float4*)(p0 + off); a1 = *(const float4*)(p1 + off);
      }
      int p = row*COLS + (col ^ ((col>>2)&7));
      tile[p] = a0; tile[NPIX + p] = a1;
    }
    __syncthreads();

    #pragma unroll
    for (int ky=0;ky<3;ky++){
      int rowb = (yr + ky)*COLS;
      float4 w0[3], w1[3];
      #pragma unroll
      for (int kx=0;kx<3;kx++){
        int tf = (ky*3+kx)*(CIN/4) + cc*2;
        w0[kx] = wsh[tf]; w1[kx] = wsh[tf+1];
      }
      #pragma unroll
      for (int j=0;j<TX+2;j++){
        int col = 4*xb + j;
        int p = rowb + (col ^ ((col>>2)&7));
        float4 a0 = tile[p], a1 = tile[NPIX + p];
        #pragma unroll
        for (int kx=0;kx<3;kx++){
          int px = j - kx;
          if (px >= 0 && px < TX){
            acc[px] += a0.x*w0[kx].x + a0.y*w0[kx].y + a0.z*w0[kx].z + a0.w*w0[kx].w
                     + a1.x*w1[kx].x + a1.y*w1[kx].y + a1.z*w1[kx].z + a1.w*w1[kx].w;
          }
        }
      }
    }
  }

  int y = y0 + yr;
  float* op = out + ((size_t)n*H + y)*(size_t)W + xbase + 4*xb;
  float4 r; r.x=acc[0]; r.y=acc[1]; r.z=acc[2]; r.w=acc[3];
  *(float4*)op = r;
}

extern "C" void kernel_launch(void* const* d_in, const int* in_sizes, int n_in,
                              void* d_out, int out_size, void* d_ws, size_t ws_size,
                              hipStream_t stream) {
  const float* x   = (const float*)d_in[0];
  const float* e1w = (const float*)d_in[1];  const float* e1b = (const float*)d_in[2];
  const float* e2w = (const float*)d_in[3];  const float* e2b = (const float*)d_in[4];
  const float* e3w = (const float*)d_in[5];  const float* e3b = (const float*)d_in[6];
  const float* e4w = (const float*)d_in[7];  const float* e4b = (const float*)d_in[8];
  const float* cb  = (const float*)d_in[9];
  const float* d1w = (const float*)d_in[10]; const float* d1b = (const float*)d_in[11];
  const float* d2w = (const float*)d_in[12]; const float* d2b = (const float*)d_in[13];
  const float* d3w = (const float*)d_in[14]; const float* d3b = (const float*)d_in[15];
  const float* d4w = (const float*)d_in[16]; const float* d4b = (const float*)d_in[17];
  float* out = (float*)d_out;

  const size_t MiB = 1ull << 20;
  int Bc = 32;
  while (Bc > 1 && (size_t)Bc * 12 * MiB > ws_size) Bc >>= 1;

  char* wsb = (char*)d_ws;
  float* A  = (float*)wsb;                              // Bc * 8 MiB
  float* Bf = (float*)(wsb + (size_t)Bc * 8 * MiB);     // Bc * 4 MiB

  for (int n0 = 0; n0 < 32; n0 += Bc) {
    const float* xc = x   + (size_t)n0 * 256*256*3;
    float*      oc  = out + (size_t)n0 * 256*256;

    // enc1: NHWC x -> h1 [Bc,8,128,128,4]; pixel/thread, grid = Bc*64
    enc1_blk_k<256,256,true><<<Bc*64,256,0,stream>>>(xc, e1w, e1b, A);
    // enc2: -> h2 [Bc,16,64,64,4]; OB=8,XB=32,TYR=8,YG=8 -> Bc*64
    conv3x3_s2_blk_k<128,128,32,64,8,2,true><<<Bc*64,256,0,stream>>>(A, e2w, e2b, Bf);
    // enc3: -> h3 [Bc,16,32,32,4]; OB=8,XB=16,TYR=16,YG=2 -> Bc*16
    conv3x3_s2_blk_k<64,64,64,64,8,2,true><<<Bc*16,256,0,stream>>>(Bf, e3w, e3b, A);
    // enc4 (1x1, 64->32) + VQ: -> q [Bc,8,32,32,4]
    int npix = Bc*32*32;
    enc4_vq_k<64,32,64,1024><<<npix/256,256,0,stream>>>(A, e4w, e4b, cb, Bf, npix);
    // dec1: q -> d1 [Bc,16,64,64,4]; XB2=16,TYR=16,YG=2,OB=8 -> Bc*16
    deconv3x3_s2_blk_k<32,32,32,64,8,2,true><<<Bc*16,256,0,stream>>>(Bf, d1w, d1b, A);
    // dec2: -> d2 [Bc,16,128,128,4]; XB2=32,TYR=8,YG=8,OB=8 -> Bc*64
    deconv3x3_s2_blk_k<64,64,64,64,8,2,true><<<Bc*64,256,0,stream>>>(A, d2w, d2b, Bf);
    // dec3: -> d3 [Bc,8,256,256,4]; XB2=64,TYR=4,YG=32,OB=4 -> Bc*128
    deconv3x3_s2_blk_k<128,128,64,32,8,2,true><<<Bc*128,256,0,stream>>>(Bf, d3w, d3b, A);
    // dec4: d3 BLOCKED -> [Bc,256,256,1]; LDS-tiled, grid = Bc*64
    dec4_tiled_k<256,256,32><<<Bc*64,256,0,stream>>>(A, d4w, d4b, oc);
  }
}

// Round 9
// 1106.222 us; speedup vs baseline: 1.4349x; 1.1003x over previous
//
#include <hip/hip_runtime.h>

#define ALPHA 0.2f
__device__ __forceinline__ float lrelu_f(float x){ return x>0.f ? x : ALPHA*x; }
__device__ __forceinline__ float4 zero4(){ float4 z; z.x=z.y=z.z=z.w=0.f; return z; }

// XCD-chunk swizzle: bijective iff grid%8==0; identity fallback otherwise.
__device__ __forceinline__ int swz_bid(){
  int nb = gridDim.x, b = blockIdx.x;
  return ((nb & 7)==0) ? ((b & 7)*(nb>>3) + (b>>3)) : b;
}

// ============ Encoder: 3x3 s2 SAME conv (pad lo=0,hi=1), NHWC in/out (r5 verified) ============
template<int H,int W,int CIN,int COUT,int TO,int TX,bool LRELU>
__global__ __launch_bounds__(256) void conv3x3_s2_k(const float* __restrict__ in,
    const float* __restrict__ w, const float* __restrict__ bias, float* __restrict__ out,
    int total){
  constexpr int Ho=H/2, Wo=W/2, OB=COUT/TO, XB=Wo/TX;
  int t = swz_bid()*256 + threadIdx.x;
  if (t >= total) return;
  int ob = t % OB; int p = t/OB;
  int xb = p % XB; p /= XB;
  int y  = p % Ho; int n = p/Ho;
  int x0 = xb*TX;

  float acc[TX][TO];
  #pragma unroll
  for (int j4=0;j4<TO/4;j4++){
    float4 bv = *(const float4*)(bias + ob*TO + j4*4);
    #pragma unroll
    for (int px=0;px<TX;px++){
      acc[px][j4*4+0]=bv.x; acc[px][j4*4+1]=bv.y;
      acc[px][j4*4+2]=bv.z; acc[px][j4*4+3]=bv.w;
    }
  }

  #pragma unroll
  for (int ky=0;ky<3;ky++){
    int iy = 2*y + ky;
    if (iy >= H) continue;
    const float* row = in + ((size_t)n*H + iy)*(size_t)(W*CIN);
    #pragma unroll
    for (int kx=0;kx<3;kx++){
      const float* wp = w + ((ky*3+kx)*CIN)*COUT + ob*TO;
      const float* ipx[TX]; bool okx[TX];
      #pragma unroll
      for (int px=0;px<TX;px++){
        int ix = 2*(x0+px)+kx;
        okx[px] = (ix < W);
        ipx[px] = row + (size_t)(okx[px] ? ix : (W-1))*CIN;
      }
      if constexpr (CIN==3){
        #pragma unroll
        for (int ci=0;ci<3;ci++){
          float4 wv[TO/4];
          #pragma unroll
          for (int j4=0;j4<TO/4;j4++) wv[j4] = *(const float4*)(wp + ci*COUT + j4*4);
          #pragma unroll
          for (int px=0;px<TX;px++){
            float v = okx[px] ? ipx[px][ci] : 0.f;
            #pragma unroll
            for (int j4=0;j4<TO/4;j4++){
              acc[px][j4*4+0] += v*wv[j4].x; acc[px][j4*4+1] += v*wv[j4].y;
              acc[px][j4*4+2] += v*wv[j4].z; acc[px][j4*4+3] += v*wv[j4].w;
            }
          }
        }
      } else {
        for (int c=0;c<CIN;c+=4){
          float4 wv[4][TO/4];
          #pragma unroll
          for (int ci=0;ci<4;ci++)
            #pragma unroll
            for (int j4=0;j4<TO/4;j4++)
              wv[ci][j4] = *(const float4*)(wp + (c+ci)*COUT + j4*4);
          #pragma unroll
          for (int px=0;px<TX;px++){
            float4 vv = *(const float4*)(ipx[px]+c);
            if (!okx[px]) vv = zero4();
            float vc[4] = {vv.x, vv.y, vv.z, vv.w};
            #pragma unroll
            for (int ci=0;ci<4;ci++)
              #pragma unroll
              for (int j4=0;j4<TO/4;j4++){
                acc[px][j4*4+0] += vc[ci]*wv[ci][j4].x;
                acc[px][j4*4+1] += vc[ci]*wv[ci][j4].y;
                acc[px][j4*4+2] += vc[ci]*wv[ci][j4].z;
                acc[px][j4*4+3] += vc[ci]*wv[ci][j4].w;
              }
          }
        }
      }
    }
  }
  #pragma unroll
  for (int px=0;px<TX;px++){
    float* op = out + ((size_t)((n*Ho+y)*Wo + x0+px))*COUT + ob*TO;
    #pragma unroll
    for (int j4=0;j4<TO/4;j4++){
      float4 r;
      r.x = LRELU?lrelu_f(acc[px][j4*4+0]):acc[px][j4*4+0];
      r.y = LRELU?lrelu_f(acc[px][j4*4+1]):acc[px][j4*4+1];
      r.z = LRELU?lrelu_f(acc[px][j4*4+2]):acc[px][j4*4+2];
      r.w = LRELU?lrelu_f(acc[px][j4*4+3]):acc[px][j4*4+3];
      *(float4*)(op+j4*4) = r;
    }
  }
}

// ============ Fused enc4 (1x1 conv 64->32) + VQ; NHWC in, q written BLOCKED (r5) ============
template<int CIN,int D,int K,int PIXI>
__global__ __launch_bounds__(256) void enc4_vq_k(const float* __restrict__ in,
    const float* __restrict__ w, const float* __restrict__ bias,
    const float* __restrict__ cb, float* __restrict__ q, int npix){
  int i = blockIdx.x*256 + threadIdx.x;
  if (i >= npix) return;
  const float* ip = in + (size_t)i*CIN;
  float z[D];
  #pragma unroll
  for (int d=0; d<D; d++) z[d] = bias[d];
  for (int c=0; c<CIN; c+=4){
    float4 v = *(const float4*)(ip + c);
    #pragma unroll
    for (int d=0; d<D; d++){
      z[d] += v.x * w[(c+0)*D + d];
      z[d] += v.y * w[(c+1)*D + d];
      z[d] += v.z * w[(c+2)*D + d];
      z[d] += v.w * w[(c+3)*D + d];
    }
  }
  float z2 = 0.f;
  #pragma unroll
  for (int d=0; d<D; d++) z2 += z[d]*z[d];
  float best = 3.4e38f; int bi = 0;
  for (int k=0; k<K; k++){
    float e2 = 0.f, dot = 0.f;
    #pragma unroll
    for (int d=0; d<D; d++){
      float cv = cb[d*K + k];
      e2  += cv*cv;
      dot += z[d]*cv;
    }
    float dist = z2 + e2 - 2.f*dot;
    if (dist < best){ best = dist; bi = k; }   // strict < == first-min (jnp.argmin)
  }
  int n = i / PIXI, pix = i % PIXI;
  #pragma unroll
  for (int p=0; p<D/4; p++){
    float4 f;
    f.x = cb[(4*p+0)*K + bi]; f.y = cb[(4*p+1)*K + bi];
    f.z = cb[(4*p+2)*K + bi]; f.w = cb[(4*p+3)*K + bi];
    *(float4*)(q + ((size_t)(n*(D/4)+p)*PIXI + pix)*4) = f;   // coalesced per plane
  }
}

// ======== Parity-fused deconv 3x3 s2 SAME, BLOCKED in/out (r5 body; TO=4/TX=4 launch) ========
template<int H,int W,int CIN,int COUT,int TO,int TX,bool LRELU>
__global__ __launch_bounds__(256) void deconv3x3_s2_blk_k(const float* __restrict__ in,
    const float* __restrict__ w, const float* __restrict__ bias, float* __restrict__ out){
  constexpr int Ho=2*H, Wo=2*W, OB=COUT/TO, XB2=W/TX, TYR=256/XB2, YG=H/TYR;
  constexpr int PI=CIN/4, PO=COUT/4;
  constexpr int WN = 9*CIN*TO;
  static_assert(256 % XB2 == 0 && H % TYR == 0, "geometry");
  __shared__ float wlds[WN];

  int lb = swz_bid();
  int ob = lb % OB; int g = lb / OB;
  int yg = g % YG;  int n  = g / YG;
  int xb = threadIdx.x % XB2, yr = threadIdx.x / XB2;
  int yy = yg*TYR + yr, x0 = xb*TX;

  {
    const int base = ob*TO;
    for (int i = threadIdx.x; i < WN/4; i += 256){
      int j4 = i % (TO/4); int rest = i / (TO/4);
      ((float4*)wlds)[i] = *(const float4*)(w + (size_t)rest*COUT + base + j4*4);
    }
  }
  __syncthreads();

  float acc[2][2*TX][TO];
  #pragma unroll
  for (int j4=0;j4<TO/4;j4++){
    float4 bv = *(const float4*)(bias + ob*TO + j4*4);
    #pragma unroll
    for (int py=0;py<2;py++)
      #pragma unroll
      for (int q=0;q<2*TX;q++){
        acc[py][q][j4*4+0]=bv.x; acc[py][q][j4*4+1]=bv.y;
        acc[py][q][j4*4+2]=bv.z; acc[py][q][j4*4+3]=bv.w;
      }
  }

  const bool has0 = (yy > 0);
  const float* nin = in + (size_t)n*PI*H*(size_t)(W*4);

  for (int pc=0; pc<PI; ++pc){
    const float* pbase = nin + (size_t)pc*H*(size_t)(W*4);
    const float* r1p = pbase + (size_t)yy*(W*4);
    const float* r0p = pbase + (size_t)(has0 ? yy-1 : 0)*(W*4);
    float4 v0[TX+1], v1[TX+1];
    #pragma unroll
    for (int j=0;j<=TX;j++){
      int xi = x0 - 1 + j;
      bool ok = (xi >= 0);
      int off = (ok ? xi : 0)*4;
      float4 a1 = *(const float4*)(r1p + off);
      float4 a0 = has0 ? *(const float4*)(r0p + off) : zero4();
      if (!ok){ a1 = zero4(); a0 = zero4(); }
      v1[j] = a1; v0[j] = a0;
    }
    const int c = pc*4;
    #pragma unroll
    for (int ky=0;ky<3;ky++){
      const int py = (ky==1) ? 1 : 0;
      #pragma unroll
      for (int kx=0;kx<3;kx++){
        const int pxp = (kx==1) ? 1 : 0;
        const float* wp = wlds + ((ky*3+kx)*CIN + c)*TO;
        float4 wv[4][TO/4];
        #pragma unroll
        for (int ci=0;ci<4;ci++)
          #pragma unroll
          for (int j4=0;j4<TO/4;j4++)
            wv[ci][j4] = *(const float4*)(wp + ci*TO + j4*4);
        #pragma unroll
        for (int px=0;px<TX;px++){
          const int jj = (kx==0) ? px : (px+1);
          float4 vv = (ky==0) ? v0[jj] : v1[jj];
          float vc[4] = {vv.x, vv.y, vv.z, vv.w};
          #pragma unroll
          for (int ci=0;ci<4;ci++)
            #pragma unroll
            for (int j4=0;j4<TO/4;j4++){
              acc[py][2*px+pxp][j4*4+0] += vc[ci]*wv[ci][j4].x;
              acc[py][2*px+pxp][j4*4+1] += vc[ci]*wv[ci][j4].y;
              acc[py][2*px+pxp][j4*4+2] += vc[ci]*wv[ci][j4].z;
              acc[py][2*px+pxp][j4*4+3] += vc[ci]*wv[ci][j4].w;
            }
        }
      }
    }
  }

  float* nout = out + (size_t)n*PO*Ho*(size_t)(Wo*4);
  #pragma unroll
  for (int py=0;py<2;py++){
    int yo = 2*yy + py;
    #pragma unroll
    for (int h2=0; h2<TO/4; ++h2){
      int pp = ob*(TO/4) + h2;
      float* op = nout + ((size_t)pp*Ho + yo)*(size_t)(Wo*4) + (size_t)(2*x0)*4;
      #pragma unroll
      for (int q=0;q<2*TX;q++){
        float4 r;
        r.x = LRELU?lrelu_f(acc[py][q][h2*4+0]):acc[py][q][h2*4+0];
        r.y = LRELU?lrelu_f(acc[py][q][h2*4+1]):acc[py][q][h2*4+1];
        r.z = LRELU?lrelu_f(acc[py][q][h2*4+2]):acc[py][q][h2*4+2];
        r.w = LRELU?lrelu_f(acc[py][q][h2*4+3]):acc[py][q][h2*4+3];
        *(float4*)(op + q*4) = r;
      }
    }
  }
}

// ============ dec4: 3x3 pad-1 conv, Cout=1 — LDS-tiled, BLOCKED input ============
template<int H,int W,int CIN>
__global__ __launch_bounds__(256) void dec4_tiled_k(const float* __restrict__ in,
    const float* __restrict__ w, const float* __restrict__ bias, float* __restrict__ out){
  constexpr int TX=4, WB=128, TYB=8, GX=W/WB, GY=H/TYB, COLS=WB+2, ROWS=TYB+2;
  constexpr int NPIX = ROWS*COLS;
  constexpr int PI = CIN/4;
  __shared__ float4 tile[2*NPIX];
  __shared__ float4 wsh[(9*CIN)/4];

  int lb = swz_bid();
  int gx = lb % GX; int rest = lb / GX;
  int yg = rest % GY; int n = rest / GY;
  int xb = threadIdx.x & 31, yr = threadIdx.x >> 5;
  int y0 = yg*TYB, xbase = gx*WB;

  if (threadIdx.x < (9*CIN)/4) wsh[threadIdx.x] = ((const float4*)w)[threadIdx.x];

  const float* nin = in + (size_t)n*PI*H*(size_t)(W*4);

  float b0 = bias[0];
  float acc[TX];
  #pragma unroll
  for (int px=0;px<TX;px++) acc[px] = b0;

  for (int cc=0; cc<CIN/8; ++cc){
    __syncthreads();
    const float* p0 = nin + (size_t)(2*cc  )*H*(size_t)(W*4);
    const float* p1 = nin + (size_t)(2*cc+1)*H*(size_t)(W*4);
    for (int i = threadIdx.x; i < NPIX; i += 256){
      int row = i / COLS, col = i % COLS;
      int grow = y0 - 1 + row, gcol = xbase - 1 + col;
      float4 a0 = zero4(), a1 = zero4();
      if ((unsigned)grow < (unsigned)H && (unsigned)gcol < (unsigned)W){
        size_t off = (size_t)grow*(W*4) + (size_t)gcol*4;
        a0 = *(const float4*)(p0 + off); a1 = *(const float4*)(p1 + off);
      }
      int p = row*COLS + (col ^ ((col>>2)&7));
      tile[p] = a0; tile[NPIX + p] = a1;
    }
    __syncthreads();

    #pragma unroll
    for (int ky=0;ky<3;ky++){
      int rowb = (yr + ky)*COLS;
      float4 w0[3], w1[3];
      #pragma unroll
      for (int kx=0;kx<3;kx++){
        int tf = (ky*3+kx)*(CIN/4) + cc*2;
        w0[kx] = wsh[tf]; w1[kx] = wsh[tf+1];
      }
      #pragma unroll
      for (int j=0;j<TX+2;j++){
        int col = 4*xb + j;
        int p = rowb + (col ^ ((col>>2)&7));
        float4 a0 = tile[p], a1 = tile[NPIX + p];
        #pragma unroll
        for (int kx=0;kx<3;kx++){
          int px = j - kx;
          if (px >= 0 && px < TX){
            acc[px] += a0.x*w0[kx].x + a0.y*w0[kx].y + a0.z*w0[kx].z + a0.w*w0[kx].w
                     + a1.x*w1[kx].x + a1.y*w1[kx].y + a1.z*w1[kx].z + a1.w*w1[kx].w;
          }
        }
      }
    }
  }

  int y = y0 + yr;
  float* op = out + ((size_t)n*H + y)*(size_t)W + xbase + 4*xb;
  float4 r; r.x=acc[0]; r.y=acc[1]; r.z=acc[2]; r.w=acc[3];
  *(float4*)op = r;
}

extern "C" void kernel_launch(void* const* d_in, const int* in_sizes, int n_in,
                              void* d_out, int out_size, void* d_ws, size_t ws_size,
                              hipStream_t stream) {
  const float* x   = (const float*)d_in[0];
  const float* e1w = (const float*)d_in[1];  const float* e1b = (const float*)d_in[2];
  const float* e2w = (const float*)d_in[3];  const float* e2b = (const float*)d_in[4];
  const float* e3w = (const float*)d_in[5];  const float* e3b = (const float*)d_in[6];
  const float* e4w = (const float*)d_in[7];  const float* e4b = (const float*)d_in[8];
  const float* cb  = (const float*)d_in[9];
  const float* d1w = (const float*)d_in[10]; const float* d1b = (const float*)d_in[11];
  const float* d2w = (const float*)d_in[12]; const float* d2b = (const float*)d_in[13];
  const float* d3w = (const float*)d_in[14]; const float* d3b = (const float*)d_in[15];
  const float* d4w = (const float*)d_in[16]; const float* d4b = (const float*)d_in[17];
  float* out = (float*)d_out;

  const size_t MiB = 1ull << 20;
  int Bc = 32;
  while (Bc > 1 && (size_t)Bc * 12 * MiB > ws_size) Bc >>= 1;

  char* wsb = (char*)d_ws;
  float* A  = (float*)wsb;                              // Bc * 8 MiB
  float* Bf = (float*)(wsb + (size_t)Bc * 8 * MiB);     // Bc * 4 MiB

  for (int n0 = 0; n0 < 32; n0 += Bc) {
    const float* xc = x   + (size_t)n0 * 256*256*3;
    float*      oc  = out + (size_t)n0 * 256*256;

    // enc1: [Bc,256,256,3] -> [Bc,128,128,32] NHWC
    int t1 = Bc*128*64*4;
    conv3x3_s2_k<256,256,3,32,8,2,true><<<t1/256,256,0,stream>>>(xc, e1w, e1b, A, t1);
    // enc2: -> [Bc,64,64,64] NHWC
    int t2 = Bc*64*32*8;
    conv3x3_s2_k<128,128,32,64,8,2,true><<<t2/256,256,0,stream>>>(A, e2w, e2b, Bf, t2);
    // enc3: -> [Bc,32,32,64] NHWC
    int t3 = Bc*32*16*8;
    conv3x3_s2_k<64,64,64,64,8,2,true><<<t3/256,256,0,stream>>>(Bf, e3w, e3b, A, t3);
    // enc4 (1x1, 64->32) + VQ: NHWC in -> q [Bc,8,32,32,4] BLOCKED
    int npix = Bc*32*32;
    enc4_vq_k<64,32,64,1024><<<npix/256,256,0,stream>>>(A, e4w, e4b, cb, Bf, npix);
    // dec1: q -> d1 [Bc,16,64,64,4]; TO=4/TX=4: OB=16,XB2=8,TYR=32,YG=1 -> Bc*16
    deconv3x3_s2_blk_k<32,32,32,64,4,4,true><<<Bc*16,256,0,stream>>>(Bf, d1w, d1b, A);
    // dec2: -> d2 [Bc,16,128,128,4]; TO=4/TX=4: OB=16,XB2=16,TYR=16,YG=4 -> Bc*64
    deconv3x3_s2_blk_k<64,64,64,64,4,4,true><<<Bc*64,256,0,stream>>>(A, d2w, d2b, Bf);
    // dec3: -> d3 [Bc,8,256,256,4]; TO=4/TX=4: OB=8,XB2=32,TYR=8,YG=16 -> Bc*128
    deconv3x3_s2_blk_k<128,128,64,32,4,4,true><<<Bc*128,256,0,stream>>>(Bf, d3w, d3b, A);
    // dec4: d3 BLOCKED -> [Bc,256,256,1]; LDS-tiled, grid = Bc*64
    dec4_tiled_k<256,256,32><<<Bc*64,256,0,stream>>>(A, d4w, d4b, oc);
  }
}

// Round 10
// 1054.869 us; speedup vs baseline: 1.5048x; 1.0487x over previous
//
#include <hip/hip_runtime.h>

#define ALPHA 0.2f
__device__ __forceinline__ float lrelu_f(float x){ return x>0.f ? x : ALPHA*x; }
__device__ __forceinline__ float4 zero4(){ float4 z; z.x=z.y=z.z=z.w=0.f; return z; }

// XCD-chunk swizzle: bijective iff grid%8==0; identity fallback otherwise.
__device__ __forceinline__ int swz_bid(){
  int nb = gridDim.x, b = blockIdx.x;
  return ((nb & 7)==0) ? ((b & 7)*(nb>>3) + (b>>3)) : b;
}

// ============ Encoder: 3x3 s2 SAME conv (pad lo=0,hi=1), NHWC in/out (r5 verified) ============
template<int H,int W,int CIN,int COUT,int TO,int TX,bool LRELU>
__global__ __launch_bounds__(256) void conv3x3_s2_k(const float* __restrict__ in,
    const float* __restrict__ w, const float* __restrict__ bias, float* __restrict__ out,
    int total){
  constexpr int Ho=H/2, Wo=W/2, OB=COUT/TO, XB=Wo/TX;
  int t = swz_bid()*256 + threadIdx.x;
  if (t >= total) return;
  int ob = t % OB; int p = t/OB;
  int xb = p % XB; p /= XB;
  int y  = p % Ho; int n = p/Ho;
  int x0 = xb*TX;

  float acc[TX][TO];
  #pragma unroll
  for (int j4=0;j4<TO/4;j4++){
    float4 bv = *(const float4*)(bias + ob*TO + j4*4);
    #pragma unroll
    for (int px=0;px<TX;px++){
      acc[px][j4*4+0]=bv.x; acc[px][j4*4+1]=bv.y;
      acc[px][j4*4+2]=bv.z; acc[px][j4*4+3]=bv.w;
    }
  }

  #pragma unroll
  for (int ky=0;ky<3;ky++){
    int iy = 2*y + ky;
    if (iy >= H) continue;
    const float* row = in + ((size_t)n*H + iy)*(size_t)(W*CIN);
    #pragma unroll
    for (int kx=0;kx<3;kx++){
      const float* wp = w + ((ky*3+kx)*CIN)*COUT + ob*TO;
      const float* ipx[TX]; bool okx[TX];
      #pragma unroll
      for (int px=0;px<TX;px++){
        int ix = 2*(x0+px)+kx;
        okx[px] = (ix < W);
        ipx[px] = row + (size_t)(okx[px] ? ix : (W-1))*CIN;
      }
      if constexpr (CIN==3){
        #pragma unroll
        for (int ci=0;ci<3;ci++){
          float4 wv[TO/4];
          #pragma unroll
          for (int j4=0;j4<TO/4;j4++) wv[j4] = *(const float4*)(wp + ci*COUT + j4*4);
          #pragma unroll
          for (int px=0;px<TX;px++){
            float v = okx[px] ? ipx[px][ci] : 0.f;
            #pragma unroll
            for (int j4=0;j4<TO/4;j4++){
              acc[px][j4*4+0] += v*wv[j4].x; acc[px][j4*4+1] += v*wv[j4].y;
              acc[px][j4*4+2] += v*wv[j4].z; acc[px][j4*4+3] += v*wv[j4].w;
            }
          }
        }
      } else {
        for (int c=0;c<CIN;c+=4){
          float4 wv[4][TO/4];
          #pragma unroll
          for (int ci=0;ci<4;ci++)
            #pragma unroll
            for (int j4=0;j4<TO/4;j4++)
              wv[ci][j4] = *(const float4*)(wp + (c+ci)*COUT + j4*4);
          #pragma unroll
          for (int px=0;px<TX;px++){
            float4 vv = *(const float4*)(ipx[px]+c);
            if (!okx[px]) vv = zero4();
            float vc[4] = {vv.x, vv.y, vv.z, vv.w};
            #pragma unroll
            for (int ci=0;ci<4;ci++)
              #pragma unroll
              for (int j4=0;j4<TO/4;j4++){
                acc[px][j4*4+0] += vc[ci]*wv[ci][j4].x;
                acc[px][j4*4+1] += vc[ci]*wv[ci][j4].y;
                acc[px][j4*4+2] += vc[ci]*wv[ci][j4].z;
                acc[px][j4*4+3] += vc[ci]*wv[ci][j4].w;
              }
          }
        }
      }
    }
  }
  #pragma unroll
  for (int px=0;px<TX;px++){
    float* op = out + ((size_t)((n*Ho+y)*Wo + x0+px))*COUT + ob*TO;
    #pragma unroll
    for (int j4=0;j4<TO/4;j4++){
      float4 r;
      r.x = LRELU?lrelu_f(acc[px][j4*4+0]):acc[px][j4*4+0];
      r.y = LRELU?lrelu_f(acc[px][j4*4+1]):acc[px][j4*4+1];
      r.z = LRELU?lrelu_f(acc[px][j4*4+2]):acc[px][j4*4+2];
      r.w = LRELU?lrelu_f(acc[px][j4*4+3]):acc[px][j4*4+3];
      *(float4*)(op+j4*4) = r;
    }
  }
}

// ============ Fused enc4 (1x1 conv 64->32) + VQ; NHWC in, q written BLOCKED (r5) ============
template<int CIN,int D,int K,int PIXI>
__global__ __launch_bounds__(256) void enc4_vq_k(const float* __restrict__ in,
    const float* __restrict__ w, const float* __restrict__ bias,
    const float* __restrict__ cb, float* __restrict__ q, int npix){
  int i = blockIdx.x*256 + threadIdx.x;
  if (i >= npix) return;
  const float* ip = in + (size_t)i*CIN;
  float z[D];
  #pragma unroll
  for (int d=0; d<D; d++) z[d] = bias[d];
  for (int c=0; c<CIN; c+=4){
    float4 v = *(const float4*)(ip + c);
    #pragma unroll
    for (int d=0; d<D; d++){
      z[d] += v.x * w[(c+0)*D + d];
      z[d] += v.y * w[(c+1)*D + d];
      z[d] += v.z * w[(c+2)*D + d];
      z[d] += v.w * w[(c+3)*D + d];
    }
  }
  float z2 = 0.f;
  #pragma unroll
  for (int d=0; d<D; d++) z2 += z[d]*z[d];
  float best = 3.4e38f; int bi = 0;
  for (int k=0; k<K; k++){
    float e2 = 0.f, dot = 0.f;
    #pragma unroll
    for (int d=0; d<D; d++){
      float cv = cb[d*K + k];
      e2  += cv*cv;
      dot += z[d]*cv;
    }
    float dist = z2 + e2 - 2.f*dot;
    if (dist < best){ best = dist; bi = k; }   // strict < == first-min (jnp.argmin)
  }
  int n = i / PIXI, pix = i % PIXI;
  #pragma unroll
  for (int p=0; p<D/4; p++){
    float4 f;
    f.x = cb[(4*p+0)*K + bi]; f.y = cb[(4*p+1)*K + bi];
    f.z = cb[(4*p+2)*K + bi]; f.w = cb[(4*p+3)*K + bi];
    *(float4*)(q + ((size_t)(n*(D/4)+p)*PIXI + pix)*4) = f;   // coalesced per plane
  }
}

// ======== Parity-fused deconv 3x3 s2 SAME, BLOCKED in/out (r5 body) ========
// TX picks wave geometry: XB2=W/TX lanes per row-group. Single-row waves (XB2>=64)
// minimize TA address-groups per load instr — the measured limiter (dec3 evidence).
template<int H,int W,int CIN,int COUT,int TO,int TX,bool LRELU>
__global__ __launch_bounds__(256) void deconv3x3_s2_blk_k(const float* __restrict__ in,
    const float* __restrict__ w, const float* __restrict__ bias, float* __restrict__ out){
  constexpr int Ho=2*H, Wo=2*W, OB=COUT/TO, XB2=W/TX, TYR=256/XB2, YG=H/TYR;
  constexpr int PI=CIN/4, PO=COUT/4;
  constexpr int WN = 9*CIN*TO;
  static_assert(256 % XB2 == 0 && H % TYR == 0, "geometry");
  __shared__ float wlds[WN];

  int lb = swz_bid();
  int ob = lb % OB; int g = lb / OB;
  int yg = g % YG;  int n  = g / YG;
  int xb = threadIdx.x % XB2, yr = threadIdx.x / XB2;
  int yy = yg*TYR + yr, x0 = xb*TX;

  {
    const int base = ob*TO;
    for (int i = threadIdx.x; i < WN/4; i += 256){
      int j4 = i % (TO/4); int rest = i / (TO/4);
      ((float4*)wlds)[i] = *(const float4*)(w + (size_t)rest*COUT + base + j4*4);
    }
  }
  __syncthreads();

  float acc[2][2*TX][TO];
  #pragma unroll
  for (int j4=0;j4<TO/4;j4++){
    float4 bv = *(const float4*)(bias + ob*TO + j4*4);
    #pragma unroll
    for (int py=0;py<2;py++)
      #pragma unroll
      for (int q=0;q<2*TX;q++){
        acc[py][q][j4*4+0]=bv.x; acc[py][q][j4*4+1]=bv.y;
        acc[py][q][j4*4+2]=bv.z; acc[py][q][j4*4+3]=bv.w;
      }
  }

  const bool has0 = (yy > 0);
  const float* nin = in + (size_t)n*PI*H*(size_t)(W*4);

  for (int pc=0; pc<PI; ++pc){
    const float* pbase = nin + (size_t)pc*H*(size_t)(W*4);
    const float* r1p = pbase + (size_t)yy*(W*4);
    const float* r0p = pbase + (size_t)(has0 ? yy-1 : 0)*(W*4);
    float4 v0[TX+1], v1[TX+1];
    #pragma unroll
    for (int j=0;j<=TX;j++){
      int xi = x0 - 1 + j;
      bool ok = (xi >= 0);
      int off = (ok ? xi : 0)*4;
      float4 a1 = *(const float4*)(r1p + off);
      float4 a0 = has0 ? *(const float4*)(r0p + off) : zero4();
      if (!ok){ a1 = zero4(); a0 = zero4(); }
      v1[j] = a1; v0[j] = a0;
    }
    const int c = pc*4;
    #pragma unroll
    for (int ky=0;ky<3;ky++){
      const int py = (ky==1) ? 1 : 0;
      #pragma unroll
      for (int kx=0;kx<3;kx++){
        const int pxp = (kx==1) ? 1 : 0;
        const float* wp = wlds + ((ky*3+kx)*CIN + c)*TO;
        float4 wv[4][TO/4];
        #pragma unroll
        for (int ci=0;ci<4;ci++)
          #pragma unroll
          for (int j4=0;j4<TO/4;j4++)
            wv[ci][j4] = *(const float4*)(wp + ci*TO + j4*4);
        #pragma unroll
        for (int px=0;px<TX;px++){
          const int jj = (kx==0) ? px : (px+1);
          float4 vv = (ky==0) ? v0[jj] : v1[jj];
          float vc[4] = {vv.x, vv.y, vv.z, vv.w};
          #pragma unroll
          for (int ci=0;ci<4;ci++)
            #pragma unroll
            for (int j4=0;j4<TO/4;j4++){
              acc[py][2*px+pxp][j4*4+0] += vc[ci]*wv[ci][j4].x;
              acc[py][2*px+pxp][j4*4+1] += vc[ci]*wv[ci][j4].y;
              acc[py][2*px+pxp][j4*4+2] += vc[ci]*wv[ci][j4].z;
              acc[py][2*px+pxp][j4*4+3] += vc[ci]*wv[ci][j4].w;
            }
        }
      }
    }
  }

  float* nout = out + (size_t)n*PO*Ho*(size_t)(Wo*4);
  #pragma unroll
  for (int py=0;py<2;py++){
    int yo = 2*yy + py;
    #pragma unroll
    for (int h2=0; h2<TO/4; ++h2){
      int pp = ob*(TO/4) + h2;
      float* op = nout + ((size_t)pp*Ho + yo)*(size_t)(Wo*4) + (size_t)(2*x0)*4;
      #pragma unroll
      for (int q=0;q<2*TX;q++){
        float4 r;
        r.x = LRELU?lrelu_f(acc[py][q][h2*4+0]):acc[py][q][h2*4+0];
        r.y = LRELU?lrelu_f(acc[py][q][h2*4+1]):acc[py][q][h2*4+1];
        r.z = LRELU?lrelu_f(acc[py][q][h2*4+2]):acc[py][q][h2*4+2];
        r.w = LRELU?lrelu_f(acc[py][q][h2*4+3]):acc[py][q][h2*4+3];
        *(float4*)(op + q*4) = r;
      }
    }
  }
}

// ============ dec4: 3x3 pad-1 conv, Cout=1 — LDS-tiled, BLOCKED input ============
template<int H,int W,int CIN>
__global__ __launch_bounds__(256) void dec4_tiled_k(const float* __restrict__ in,
    const float* __restrict__ w, const float* __restrict__ bias, float* __restrict__ out){
  constexpr int TX=4, WB=128, TYB=8, GX=W/WB, GY=H/TYB, COLS=WB+2, ROWS=TYB+2;
  constexpr int NPIX = ROWS*COLS;
  constexpr int PI = CIN/4;
  __shared__ float4 tile[2*NPIX];
  __shared__ float4 wsh[(9*CIN)/4];

  int lb = swz_bid();
  int gx = lb % GX; int rest = lb / GX;
  int yg = rest % GY; int n = rest / GY;
  int xb = threadIdx.x & 31, yr = threadIdx.x >> 5;
  int y0 = yg*TYB, xbase = gx*WB;

  if (threadIdx.x < (9*CIN)/4) wsh[threadIdx.x] = ((const float4*)w)[threadIdx.x];

  const float* nin = in + (size_t)n*PI*H*(size_t)(W*4);

  float b0 = bias[0];
  float acc[TX];
  #pragma unroll
  for (int px=0;px<TX;px++) acc[px] = b0;

  for (int cc=0; cc<CIN/8; ++cc){
    __syncthreads();
    const float* p0 = nin + (size_t)(2*cc  )*H*(size_t)(W*4);
    const float* p1 = nin + (size_t)(2*cc+1)*H*(size_t)(W*4);
    for (int i = threadIdx.x; i < NPIX; i += 256){
      int row = i / COLS, col = i % COLS;
      int grow = y0 - 1 + row, gcol = xbase - 1 + col;
      float4 a0 = zero4(), a1 = zero4();
      if ((unsigned)grow < (unsigned)H && (unsigned)gcol < (unsigned)W){
        size_t off = (size_t)grow*(W*4) + (size_t)gcol*4;
        a0 = *(const float4*)(p0 + off); a1 = *(const float4*)(p1 + off);
      }
      int p = row*COLS + (col ^ ((col>>2)&7));
      tile[p] = a0; tile[NPIX + p] = a1;
    }
    __syncthreads();

    #pragma unroll
    for (int ky=0;ky<3;ky++){
      int rowb = (yr + ky)*COLS;
      float4 w0[3], w1[3];
      #pragma unroll
      for (int kx=0;kx<3;kx++){
        int tf = (ky*3+kx)*(CIN/4) + cc*2;
        w0[kx] = wsh[tf]; w1[kx] = wsh[tf+1];
      }
      #pragma unroll
      for (int j=0;j<TX+2;j++){
        int col = 4*xb + j;
        int p = rowb + (col ^ ((col>>2)&7));
        float4 a0 = tile[p], a1 = tile[NPIX + p];
        #pragma unroll
        for (int kx=0;kx<3;kx++){
          int px = j - kx;
          if (px >= 0 && px < TX){
            acc[px] += a0.x*w0[kx].x + a0.y*w0[kx].y + a0.z*w0[kx].z + a0.w*w0[kx].w
                     + a1.x*w1[kx].x + a1.y*w1[kx].y + a1.z*w1[kx].z + a1.w*w1[kx].w;
          }
        }
      }
    }
  }

  int y = y0 + yr;
  float* op = out + ((size_t)n*H + y)*(size_t)W + xbase + 4*xb;
  float4 r; r.x=acc[0]; r.y=acc[1]; r.z=acc[2]; r.w=acc[3];
  *(float4*)op = r;
}

extern "C" void kernel_launch(void* const* d_in, const int* in_sizes, int n_in,
                              void* d_out, int out_size, void* d_ws, size_t ws_size,
                              hipStream_t stream) {
  const float* x   = (const float*)d_in[0];
  const float* e1w = (const float*)d_in[1];  const float* e1b = (const float*)d_in[2];
  const float* e2w = (const float*)d_in[3];  const float* e2b = (const float*)d_in[4];
  const float* e3w = (const float*)d_in[5];  const float* e3b = (const float*)d_in[6];
  const float* e4w = (const float*)d_in[7];  const float* e4b = (const float*)d_in[8];
  const float* cb  = (const float*)d_in[9];
  const float* d1w = (const float*)d_in[10]; const float* d1b = (const float*)d_in[11];
  const float* d2w = (const float*)d_in[12]; const float* d2b = (const float*)d_in[13];
  const float* d3w = (const float*)d_in[14]; const float* d3b = (const float*)d_in[15];
  const float* d4w = (const float*)d_in[16]; const float* d4b = (const float*)d_in[17];
  float* out = (float*)d_out;

  const size_t MiB = 1ull << 20;
  int Bc = 32;
  while (Bc > 1 && (size_t)Bc * 12 * MiB > ws_size) Bc >>= 1;

  char* wsb = (char*)d_ws;
  float* A  = (float*)wsb;                              // Bc * 8 MiB
  float* Bf = (float*)(wsb + (size_t)Bc * 8 * MiB);     // Bc * 4 MiB

  for (int n0 = 0; n0 < 32; n0 += Bc) {
    const float* xc = x   + (size_t)n0 * 256*256*3;
    float*      oc  = out + (size_t)n0 * 256*256;

    // enc1: [Bc,256,256,3] -> [Bc,128,128,32] NHWC
    int t1 = Bc*128*64*4;
    conv3x3_s2_k<256,256,3,32,8,2,true><<<t1/256,256,0,stream>>>(xc, e1w, e1b, A, t1);
    // enc2: -> [Bc,64,64,64] NHWC
    int t2 = Bc*64*32*8;
    conv3x3_s2_k<128,128,32,64,8,2,true><<<t2/256,256,0,stream>>>(A, e2w, e2b, Bf, t2);
    // enc3: -> [Bc,32,32,64] NHWC
    int t3 = Bc*32*16*8;
    conv3x3_s2_k<64,64,64,64,8,2,true><<<t3/256,256,0,stream>>>(Bf, e3w, e3b, A, t3);
    // enc4 (1x1, 64->32) + VQ: NHWC in -> q [Bc,8,32,32,4] BLOCKED
    int npix = Bc*32*32;
    enc4_vq_k<64,32,64,1024><<<npix/256,256,0,stream>>>(A, e4w, e4b, cb, Bf, npix);
    // dec1: q -> d1 [Bc,16,64,64,4]; TX=1: XB2=32(2-row waves),TYR=8,YG=4,OB=8 -> Bc*32
    deconv3x3_s2_blk_k<32,32,32,64,8,1,true><<<Bc*32,256,0,stream>>>(Bf, d1w, d1b, A);
    // dec2: -> d2 [Bc,16,128,128,4]; TX=1: XB2=64(1-row waves),TYR=4,YG=16,OB=8 -> Bc*128
    deconv3x3_s2_blk_k<64,64,64,64,8,1,true><<<Bc*128,256,0,stream>>>(A, d2w, d2b, Bf);
    // dec3: -> d3 [Bc,8,256,256,4]; TX=2 (already 1-row waves): XB2=64,TYR=4,YG=32 -> Bc*128
    deconv3x3_s2_blk_k<128,128,64,32,8,2,true><<<Bc*128,256,0,stream>>>(Bf, d3w, d3b, A);
    // dec4: d3 BLOCKED -> [Bc,256,256,1]; LDS-tiled, grid = Bc*64
    dec4_tiled_k<256,256,32><<<Bc*64,256,0,stream>>>(A, d4w, d4b, oc);
  }
}